// Round 4
// baseline (279.067 us; speedup 1.0000x reference)
//
#include <hip/hip_runtime.h>
#include <hip/hip_bf16.h>
#include <math.h>

#define B_TOT 16384
#define T_DIM 64
#define D_DIM 32
#define K_DIM 32
#define H_DIM 32
#define L_DIM 16
#define NB 64    // batch rows per block
#define NDP 16   // d-pairs
#define LDSB 17  // padded dp-stride in uints (conflict-free: 17*4=68B, 17 coprime 32)

// ---------- prep: transpose basis [K][T] -> basisT [T][K] (tiny) ----------
__global__ void prep_transpose(const float* __restrict__ basis, float* __restrict__ basisT) {
    int i = blockIdx.x * blockDim.x + threadIdx.x;
    if (i < K_DIM * T_DIM) {
        int k = i / T_DIM, t = i % T_DIM;
        basisT[t * K_DIM + k] = basis[i];
    }
}

__device__ __forceinline__ unsigned bf16_rne(float x) {
    unsigned r = __float_as_uint(x);
    r += 0x7fffu + ((r >> 16) & 1u);
    return r >> 16;
}

__device__ __forceinline__ float gelu_exact(float x) {
    // erf via A&S 7.1.26, |eps|<=1.5e-7, branch-free
    float y = x * 0.70710678118654752f;
    float ay = fabsf(y);
    float t = __builtin_amdgcn_rcpf(fmaf(0.3275911f, ay, 1.0f));
    float p = fmaf(fmaf(fmaf(fmaf(1.061405429f, t, -1.453152027f),
                             t, 1.421413741f),
                        t, -0.284496736f),
                   t, 0.254829592f) * t;
    float e = 1.0f - p * __expf(-ay * ay);
    e = copysignf(e, y);
    return 0.5f * x * (1.0f + e);
}

// ---------- fused: projection -> LDS(bf16) -> per-k MLP + LayerNorm ----------
// 1024 thr, 64 b per block, grid=256 (1 block/CU, 136KB LDS, 4 waves/SIMD).
__global__ __launch_bounds__(1024) void fused_kernel(const float* __restrict__ sample,
                                                     const float* __restrict__ basisT,
                                                     const float* __restrict__ W1,
                                                     const float* __restrict__ b1,
                                                     const float* __restrict__ W2,
                                                     const float* __restrict__ b2,
                                                     const float* __restrict__ gamma,
                                                     const float* __restrict__ beta,
                                                     float* __restrict__ out) {
    __shared__ unsigned clds[K_DIM][NB][LDSB];  // 32*64*17*4 = 139264 B
    const int tid = threadIdx.x;

    // ===== phase 1: coeffs[k] for (b, d-pair) =====
    {
        const int bl = tid >> 4;   // 0..63
        const int dp = tid & 15;   // 0..15 -> d = 2*dp, 2*dp+1
        const long b = (long)blockIdx.x * NB + bl;

        float ax[K_DIM], ay[K_DIM];
#pragma unroll
        for (int k = 0; k < K_DIM; ++k) { ax[k] = 0.f; ay[k] = 0.f; }

        const float2* sp = reinterpret_cast<const float2*>(sample + b * (T_DIM * D_DIM)) + dp;
#pragma unroll 4
        for (int t = 0; t < T_DIM; ++t) {
            float2 sv = sp[t * NDP];                 // coalesced 8B/lane stream
            const float* bt = basisT + t * K_DIM;    // wave-uniform -> s_load
#pragma unroll
            for (int k = 0; k < K_DIM; ++k) {
                ax[k] = fmaf(bt[k], sv.x, ax[k]);
                ay[k] = fmaf(bt[k], sv.y, ay[k]);
            }
        }
#pragma unroll
        for (int k = 0; k < K_DIM; ++k)
            clds[k][bl][dp] = bf16_rne(ax[k]) | (bf16_rne(ay[k]) << 16);
    }
    __syncthreads();

    // ===== phase 2: per (b,k) MLP + LN; wave = 64 b's at one k =====
    {
        const int w = tid >> 6;        // 0..15
        const int lane = tid & 63;     // = b_local
        const long b = (long)blockIdx.x * NB + lane;

#pragma unroll 1
        for (int rep = 0; rep < 2; ++rep) {
            const int k = __builtin_amdgcn_readfirstlane(w + rep * 16);

            // coeffs from LDS (conflict-free: lane stride 68B, 17 coprime 32)
            float cv[D_DIM];
#pragma unroll
            for (int dp = 0; dp < NDP; ++dp) {
                unsigned u = clds[k][lane][dp];
                cv[2 * dp]     = __uint_as_float(u << 16);
                cv[2 * dp + 1] = __uint_as_float(u & 0xffff0000u);
            }

            // layer 1 (weights: scalar loads, k uniform)
            const float* w1p = W1 + k * (D_DIM * H_DIM);
            const float* b1p = b1 + k * H_DIM;
            float h[H_DIM];
#pragma unroll
            for (int j = 0; j < H_DIM; ++j) h[j] = b1p[j];
#pragma unroll 4
            for (int d = 0; d < D_DIM; ++d) {
                const float* wr = w1p + d * H_DIM;
                float c = cv[d];
#pragma unroll
                for (int j = 0; j < H_DIM; ++j) h[j] = fmaf(c, wr[j], h[j]);
            }

#pragma unroll
            for (int j = 0; j < H_DIM; ++j) h[j] = gelu_exact(h[j]);

            // layer 2
            const float* w2p = W2 + k * (H_DIM * L_DIM);
            const float* b2p = b2 + k * L_DIM;
            float z[L_DIM];
#pragma unroll
            for (int l = 0; l < L_DIM; ++l) z[l] = b2p[l];
#pragma unroll 4
            for (int hh = 0; hh < H_DIM; ++hh) {
                const float* wr = w2p + hh * L_DIM;
                float hv = h[hh];
#pragma unroll
                for (int l = 0; l < L_DIM; ++l) z[l] = fmaf(hv, wr[l], z[l]);
            }

            // LayerNorm over L=16 (thread-local)
            float mu = 0.f;
#pragma unroll
            for (int l = 0; l < L_DIM; ++l) mu += z[l];
            mu *= (1.0f / L_DIM);
            float var = 0.f;
#pragma unroll
            for (int l = 0; l < L_DIM; ++l) { float dz = z[l] - mu; var = fmaf(dz, dz, var); }
            var *= (1.0f / L_DIM);
            float rstd = rsqrtf(var + 1e-5f);

            float4 o[4];
            float* of = reinterpret_cast<float*>(o);
#pragma unroll
            for (int l = 0; l < L_DIM; ++l) of[l] = fmaf(gamma[l] * rstd, z[l] - mu, beta[l]);

            float4* op = reinterpret_cast<float4*>(out + (b * K_DIM + k) * L_DIM);
#pragma unroll
            for (int q = 0; q < 4; ++q) op[q] = o[q];
        }
    }
}

extern "C" void kernel_launch(void* const* d_in, const int* in_sizes, int n_in,
                              void* d_out, int out_size, void* d_ws, size_t ws_size,
                              hipStream_t stream) {
    const float* sample = (const float*)d_in[0];
    const float* basis  = (const float*)d_in[1];
    const float* W1     = (const float*)d_in[2];
    const float* b1     = (const float*)d_in[3];
    const float* W2     = (const float*)d_in[4];
    const float* b2     = (const float*)d_in[5];
    const float* gamma  = (const float*)d_in[6];
    const float* beta   = (const float*)d_in[7];
    float* out = (float*)d_out;

    float* basisT = (float*)d_ws;  // 8 KB scratch only

    prep_transpose<<<8, 256, 0, stream>>>(basis, basisT);
    fused_kernel<<<B_TOT / NB, 1024, 0, stream>>>(sample, basisT, W1, b1, W2, b2,
                                                  gamma, beta, out);
}